// Round 14
// baseline (55.591 us; speedup 1.0000x reference)
//
#include <hip/hip_runtime.h>
#include <math.h>

// TaskAdaptiveRouter via split-bf16 4-pass MFMA.
// R13 = R12 structure at 32-token blocks, grid 512 -> 2 blocks/CU co-residency.
// LDS trimmed to 34.8 KB (2-deep B ring 32KB, lg 17.4KB ALIASED into ring, pf 2KB):
// 2 x 34.8 = 69.6 KB <= R11's proven-allocatable 68.6KB single-block footprint.
// R12 lesson: grid 256 = 1 block/CU by construction - occupancy lever needs grid>=512.
// 2-deep ring race-free: producer writes buf[(t+1)&1] during step t; consumers'
// step-(t-1) reads of that parity retired (compiler lgkm wait precedes MFMA use,
// which precedes the barrier). Producer vmcnt(0)/step covered by step length.
// Queues disjoint: producer vmcnt = B-DMA only; consumer vmcnt = x ring only.
//
// d_out (f32): [0,32768) topw ; [32768,65536) topi(float) ; [65536,1114112) probs ;
//              [1114112] aux.
// d_ws: [0,256) tl[4][64] ; [256,1280) P/F slots ; [1280..) W B-frags wh,wl
//       (65536 u32 each). B-frag: dword ((s*4+g)*64+lane)*4+d ; s=k>>5 in [0,64).

#define DDIM 2048
#define WROW 2064

typedef unsigned int u32;
typedef unsigned short u16;
typedef unsigned long long u64;
using short8 = __attribute__((ext_vector_type(8))) short;
using f32x4  = __attribute__((ext_vector_type(4))) float;

typedef const __attribute__((address_space(1))) u32* gp1;
typedef __attribute__((address_space(3))) u32* lp3;

#define BAR() do {                                                              \
        __builtin_amdgcn_s_barrier();                                           \
        asm volatile("" ::: "memory");                                          \
        __builtin_amdgcn_sched_barrier(0);                                      \
    } while (0)

__device__ __forceinline__ u16 bf16rne(float f) {
    u32 u = __float_as_uint(f);
    return (u16)((u + 0x7FFFu + ((u >> 16) & 1u)) >> 16);
}

// ---------------- kernel 0: build W B-fragments (hi/lo bf16) ----------------------
__global__ void k0_wsplit(const float* __restrict__ Wr, u32* __restrict__ wh,
                          u32* __restrict__ wl) {
    const int g = blockIdx.x * 256 + threadIdx.x;    // 0..65535
    const int e  = g >> 10;                          // expert 0..63
    const int kp = g & 1023;                         // k-pair 0..1023
    const int k  = kp * 2;
    const int step = k >> 5, kb = (k >> 3) & 3, d = (k >> 1) & 3;
    const int grp = e >> 4, lane = kb * 16 + (e & 15);
    const float w0 = Wr[(size_t)e * WROW + k];
    const float w1 = Wr[(size_t)e * WROW + k + 1];
    const u16 h0 = bf16rne(w0);
    const u16 h1 = bf16rne(w1);
    const u16 l0 = bf16rne(w0 - __uint_as_float((u32)h0 << 16));
    const u16 l1 = bf16rne(w1 - __uint_as_float((u32)h1 << 16));
    const u32 oi = (u32)(((step * 4 + grp) * 64 + lane) * 4 + d);
    wh[oi] = ((u32)h1 << 16) | h0;
    wl[oi] = ((u32)l1 << 16) | l0;
}

// ---------------- kernel 1: task proj + task logits + zero P/F slots -------------
__global__ void k1_task(const float* __restrict__ z, const float* __restrict__ Wp,
                        const float* __restrict__ bp, const float* __restrict__ Wr,
                        const float* __restrict__ eb, float* __restrict__ wsb) {
    __shared__ float tp[4][16];
    const int t = threadIdx.x;
    if (t < 64) {
        const int b = t >> 4, r = t & 15;
        float s = bp[r];
        #pragma unroll
        for (int i = 0; i < 16; ++i) s += z[b * 16 + i] * Wp[r * 16 + i];
        tp[b][r] = 0.5f * s * (1.0f + erff(s * 0.70710678118654752440f));
    }
    #pragma unroll
    for (int i = t; i < 1024; i += 256) wsb[256 + i] = 0.0f;   // zero 8 P/F slots
    __syncthreads();
    {
        const int b = t >> 6, e = t & 63;
        const float* wr = Wr + (size_t)e * WROW + DDIM;
        float s = eb[e];
        #pragma unroll
        for (int i = 0; i < 16; ++i) s += tp[b][i] * wr[i];
        wsb[b * 64 + e] = s;
    }
}

// ---------------- kernel 2: MFMA logits + softmax + top2 + probs + P/f -----------
// 320 thr: waves 0..3 consumers (tg = wv&1 token group, h = wv>>1 K-half),
// wave 4 producer (B-frags -> 2-deep LDS ring).
// LDS: smem[0..8192) u32 = B ring 2x16KB ; lg (f32[2][32*68], 17.4KB) ALIASES ring;
// pf = smem[8192..8704) (2KB). Total 34.8 KB -> 2 blocks/CU at grid 512.
__global__ __launch_bounds__(320, 2) void k2_mfma(const float* __restrict__ x,
                                                  const float* __restrict__ wsb,
                                                  const u32* __restrict__ whp,
                                                  const u32* __restrict__ wlp,
                                                  float* __restrict__ wacc,
                                                  float* __restrict__ out) {
    __shared__ __align__(16) u32 smem[8704];       // 34.8 KB total
    float* const lgf = (float*)smem;               // [2][32*68], post-loop only
    float* const pff = (float*)&smem[8192];        // [4*128]

    const int tid   = threadIdx.x;
    const int wv    = __builtin_amdgcn_readfirstlane(tid >> 6);
    const int lane  = tid & 63;
    const int tok0b = blockIdx.x * 32;
    const int bb    = tok0b >> 12;    // batch (uniform per block)

    if (wv == 4) {
        // ---- producer: B-frag DMA, 2-deep ring; vmcnt = DMAs only ----------------
#define BDMA(t, buf) do {                                                       \
            _Pragma("unroll")                                                   \
            for (int hl = 0; hl < 2; ++hl)                                      \
            _Pragma("unroll")                                                   \
            for (int hh = 0; hh < 2; ++hh)                                      \
            _Pragma("unroll")                                                   \
            for (int g = 0; g < 4; ++g) {                                       \
                const u32* _s = (hl ? wlp : whp) +                              \
                                ((t) + hh * 32) * 1024 + g * 256 + lane * 4;    \
                u32* _d = &smem[(buf) * 4096 + hl * 2048 + hh * 1024 + g * 256 + lane * 4];\
                __builtin_amdgcn_global_load_lds((gp1)_s, (lp3)_d, 16, 0, 0);   \
            }                                                                   \
        } while (0)
        BDMA(0, 0);
        asm volatile("s_waitcnt vmcnt(0)" ::: "memory");
        BAR();                                    // B(0) ready; consumers start t=0
        for (int t = 0; t < 32; ++t) {
            if (t + 1 < 32) {
                BDMA(t + 1, (t + 1) & 1);         // into the buffer NOT being read
                asm volatile("s_waitcnt vmcnt(0)" ::: "memory");  // covered by step len
            }
            BAR();                                // end of step t; B(t+1) ready
        }
#undef BDMA
    } else {
        // ---------------- consumer: vmcnt = x ring only ---------------------------
        const int tg  = wv & 1;
        const int h   = wv >> 1;
        const int row = lane & 15;    // token within 16-tile (A row)
        const int kg  = lane >> 4;    // k-group 0..3
        const int tok0 = tok0b + tg * 16;

        f32x4 acc[4];
        #pragma unroll
        for (int g = 0; g < 4; ++g) {
            const float tl = (h == 0) ? wsb[bb * 64 + g * 16 + row] : 0.0f;
            acc[g] = (f32x4){tl, tl, tl, tl};
        }
        #pragma unroll
        for (int g = 0; g < 4; ++g) asm volatile("" : "+v"(acc[g]));
        __builtin_amdgcn_sched_barrier(0);       // wsb-load wait lands before ring

        const u64 xaddr = (u64)(x + (size_t)(tok0 + row) * DDIM + h * 1024 + kg * 8);
        f32x4 xr[6][2];                          // depth-6 ring (48 VGPR)

#define XLOAD(i, T) do {                                                        \
            asm volatile("global_load_dwordx4 %0, %1, off offset:%c2"           \
                : "=&v"(xr[i][0]) : "v"(xaddr), "i"((T) * 128));                \
            asm volatile("global_load_dwordx4 %0, %1, off offset:%c2"           \
                : "=&v"(xr[i][1]) : "v"(xaddr), "i"((T) * 128 + 16));           \
        } while (0)

#define XWAIT(i) do {                                                           \
            asm volatile("s_waitcnt vmcnt(10)"                                  \
                : "+v"(xr[i][0]), "+v"(xr[i][1]));                              \
            __builtin_amdgcn_sched_barrier(0);                                  \
        } while (0)

#define MSTEP(xa, xb, BH, BL) do {                                              \
            float vv[8];                                                        \
            _Pragma("unroll")                                                   \
            for (int j = 0; j < 4; ++j) { vv[j] = (xa)[j]; vv[4 + j] = (xb)[j]; }\
            short8 Ah, Al;                                                      \
            _Pragma("unroll")                                                   \
            for (int j = 0; j < 8; ++j) {                                       \
                const float v = vv[j];                                          \
                const u16 hh = bf16rne(v);                                      \
                const u16 ll = bf16rne(v - __uint_as_float((u32)hh << 16));     \
                Ah[j] = (short)hh; Al[j] = (short)ll;                           \
            }                                                                   \
            _Pragma("unroll")                                                   \
            for (int g = 0; g < 4; ++g) {                                       \
                acc[g] = __builtin_amdgcn_mfma_f32_16x16x32_bf16(Ah, BH[g], acc[g], 0, 0, 0); \
                acc[g] = __builtin_amdgcn_mfma_f32_16x16x32_bf16(Ah, BL[g], acc[g], 0, 0, 0); \
                acc[g] = __builtin_amdgcn_mfma_f32_16x16x32_bf16(Al, BH[g], acc[g], 0, 0, 0); \
                acc[g] = __builtin_amdgcn_mfma_f32_16x16x32_bf16(Al, BL[g], acc[g], 0, 0, 0); \
            }                                                                   \
        } while (0)

        XLOAD(0, 0); XLOAD(1, 1); XLOAD(2, 2);
        XLOAD(3, 3); XLOAD(4, 4); XLOAD(5, 5);
        BAR();                                   // B(0) ready
        #pragma unroll
        for (int t = 0; t < 32; ++t) {
            short8 BH[4], BL[4];
            #pragma unroll
            for (int g = 0; g < 4; ++g) {       // B(t) from LDS (lgkm; MFMA-dep drained)
                BH[g] = *(const short8*)&smem[(t & 1) * 4096 + h * 1024 + g * 256 + lane * 4];
                BL[g] = *(const short8*)&smem[(t & 1) * 4096 + 2048 + h * 1024 + g * 256 + lane * 4];
            }
            XWAIT(t % 6);                        // static: 10 newer x-loads outstanding
            MSTEP(xr[t % 6][0], xr[t % 6][1], BH, BL);
            XLOAD(t % 6, (t + 6) & 31);          // wrap-issue keeps vmcnt geometry exact
            BAR();                               // done reading buf t&1; B(t+1) ready
        }
        // drain dangling ring loads before VGPR reuse in epilogue
        asm volatile("s_waitcnt vmcnt(0)"
            : "+v"(xr[0][0]), "+v"(xr[0][1]), "+v"(xr[1][0]), "+v"(xr[1][1]),
              "+v"(xr[2][0]), "+v"(xr[2][1]), "+v"(xr[3][0]), "+v"(xr[3][1]),
              "+v"(xr[4][0]), "+v"(xr[4][1]), "+v"(xr[5][0]), "+v"(xr[5][1]));
        __builtin_amdgcn_sched_barrier(0);
#undef XLOAD
#undef XWAIT
#undef MSTEP

        // ---- partial-logit exchange into ALIASED lg (post-loop only) -------------
        #pragma unroll
        for (int g = 0; g < 4; ++g)
            #pragma unroll
            for (int r = 0; r < 4; ++r)
                lgf[h * 2176 + (tg * 16 + kg * 4 + r) * 68 + g * 16 + row] = acc[g][r];
    }

    __syncthreads();

    // ---- softmax/top2 for tokens wv*8 .. wv*8+7 ; lane = expert (consumers) ----
    if (wv < 4) {
        float pacc = 0.0f, facc = 0.0f;
        for (int i = 0; i < 8; ++i) {
            const int tk = wv * 8 + i;
            const float v = lgf[tk * 68 + lane] + lgf[2176 + tk * 68 + lane];
            float m1 = v; int i1 = lane;
            #pragma unroll
            for (int off = 32; off; off >>= 1) {
                const float ov = __shfl_xor(m1, off, 64);
                const int   oi = __shfl_xor(i1, off, 64);
                if (ov > m1 || (ov == m1 && oi < i1)) { m1 = ov; i1 = oi; }
            }
            const float vx = (lane == i1) ? -3.4e38f : v;
            float m2 = vx; int i2 = lane;
            #pragma unroll
            for (int off = 32; off; off >>= 1) {
                const float ov = __shfl_xor(m2, off, 64);
                const int   oi = __shfl_xor(i2, off, 64);
                if (ov > m2 || (ov == m2 && oi < i2)) { m2 = ov; i2 = oi; }
            }
            const float p = __expf(v - m1);
            float s = p;
            #pragma unroll
            for (int off = 32; off; off >>= 1) s += __shfl_xor(s, off, 64);
            const float rZ = 1.0f / s;
            const float pn = p * rZ;
            const int   T  = tok0b + tk;
            out[65536 + (size_t)T * 64 + lane] = pn;      // coalesced 256 B
            pacc += pn;
            facc += (lane == i1 ? 1.0f : 0.0f) + (lane == i2 ? 1.0f : 0.0f);
            if (lane == 0) {
                const float q1 = rZ, q2 = __expf(m2 - m1) * rZ;
                const float dn = 1.0f / (q1 + q2 + 1e-8f);
                float2 tw; tw.x = q1 * dn; tw.y = q2 * dn;
                *(float2*)(out + (size_t)T * 2) = tw;
                float2 ti; ti.x = (float)i1; ti.y = (float)i2;
                *(float2*)(out + 32768 + (size_t)T * 2) = ti;
            }
        }
        pff[wv * 128 + lane]      = pacc;
        pff[wv * 128 + 64 + lane] = facc;
    }
    __syncthreads();

    // ---- block-level P/f reduce -> one atomic per address per block (8 slots) ----
    if (wv == 0) {
        float ps = 0.0f, fs = 0.0f;
        #pragma unroll
        for (int w2 = 0; w2 < 4; ++w2) {
            ps += pff[w2 * 128 + lane];
            fs += pff[w2 * 128 + 64 + lane];
        }
        const int slot = blockIdx.x & 7;
        atomicAdd(wacc + slot * 128 + lane, ps);
        atomicAdd(wacc + slot * 128 + 64 + lane, fs);
    }
}

// ---------------- kernel 3: aux loss ------------------------------------------------
__global__ void k3_aux(const float* __restrict__ wsb, float* __restrict__ out) {
    const int e = threadIdx.x;  // 64 threads
    float P = 0.0f, F = 0.0f;
    #pragma unroll
    for (int s = 0; s < 8; ++s) {
        P += wsb[256 + s * 128 + e];
        F += wsb[256 + s * 128 + 64 + e];
    }
    float val = P * F;
    #pragma unroll
    for (int off = 32; off; off >>= 1) val += __shfl_xor(val, off, 64);
    if (e == 0)
        out[1114112] = 64.0f * val / (16384.0f * 2.0f * 16384.0f);
}

extern "C" void kernel_launch(void* const* d_in, const int* in_sizes, int n_in,
                              void* d_out, int out_size, void* d_ws, size_t ws_size,
                              hipStream_t stream) {
    (void)in_sizes; (void)n_in; (void)out_size; (void)ws_size;
    const float* x  = (const float*)d_in[0];
    const float* z  = (const float*)d_in[1];
    const float* Wr = (const float*)d_in[2];
    const float* Wp = (const float*)d_in[3];
    const float* bp = (const float*)d_in[4];
    const float* eb = (const float*)d_in[5];
    float* out = (float*)d_out;
    float* wsb = (float*)d_ws;
    u32*   wfH = (u32*)(wsb + 1280);          // 65536 u32 (256 KB)
    u32*   wfL = wfH + 65536;                 // 65536 u32 (256 KB)

    hipLaunchKernelGGL(k0_wsplit, dim3(256), dim3(256), 0, stream, Wr, wfH, wfL);
    hipLaunchKernelGGL(k1_task,   dim3(1),   dim3(256), 0, stream, z, Wp, bp, Wr, eb, wsb);
    hipLaunchKernelGGL(k2_mfma,   dim3(512), dim3(320), 0, stream, x, wsb,
                       wfH, wfL, wsb + 256, out);
    hipLaunchKernelGGL(k3_aux,    dim3(1),   dim3(64),  0, stream, wsb, out);
}

// Round 15
// 45.853 us; speedup vs baseline: 1.2124x; 1.2124x over previous
//
#include <hip/hip_runtime.h>
#include <math.h>

// TaskAdaptiveRouter via split-bf16 4-pass MFMA.
// R14 = R12 (best, 49.7us) + (1) rolled main loop (7 groups x 4 static steps +
// 4-step epilogue; x-ring depth 4 t&3, B-ring 4-deep t&3, addr +512B/group) to
// kill I$ pressure from the old ~4000-inst fully-unrolled loop; (2) split via
// v_cvt_pk_bf16_f32 (1 inst per f32-pair, RNE == manual) cutting split VALU ~4x;
// (3) k1 merged into k0. Queues stay disjoint: producer vmcnt = B-DMA only
// (steady vmcnt(32), never drains mid-loop); consumer vmcnt = x-ring only
// (steady vmcnt(6), epilogue 6/4/2/0 self-draining); B via ds_read (lgkm).
//
// d_out (f32): [0,32768) topw ; [32768,65536) topi(float) ; [65536,1114112) probs ;
//              [1114112] aux.
// d_ws: [0,256) tl[4][64] ; [256,1280) P/F slots ; [1280..) W B-frags wh,wl
//       (65536 u32 each). B-frag: dword ((s*4+g)*64+lane)*4+d ; s=k>>5 in [0,64).

#define DDIM 2048
#define WROW 2064

typedef unsigned int u32;
typedef unsigned short u16;
typedef unsigned long long u64;
using short8 = __attribute__((ext_vector_type(8))) short;
using f32x4  = __attribute__((ext_vector_type(4))) float;
using u32x4  = __attribute__((ext_vector_type(4))) u32;

typedef const __attribute__((address_space(1))) u32* gp1;
typedef __attribute__((address_space(3))) u32* lp3;

#define BAR() do {                                                              \
        __builtin_amdgcn_s_barrier();                                           \
        asm volatile("" ::: "memory");                                          \
        __builtin_amdgcn_sched_barrier(0);                                      \
    } while (0)

__device__ __forceinline__ u16 bf16rne(float f) {
    u32 u = __float_as_uint(f);
    return (u16)((u + 0x7FFFu + ((u >> 16) & 1u)) >> 16);
}

// ---------------- kernel 01: W B-fragments + task logits + zero P/F ---------------
__global__ void k01_prep(const float* __restrict__ Wr, u32* __restrict__ wh,
                         u32* __restrict__ wl, const float* __restrict__ z,
                         const float* __restrict__ Wp, const float* __restrict__ bp,
                         const float* __restrict__ eb, float* __restrict__ wsb) {
    const int t = threadIdx.x;
    if (blockIdx.x < 256) {
        const int g = blockIdx.x * 256 + t;              // 0..65535
        const int e  = g >> 10;                          // expert 0..63
        const int k  = (g & 1023) * 2;                   // k-pair base
        const int step = k >> 5, kb = (k >> 3) & 3, d = (k >> 1) & 3;
        const int grp = e >> 4, lane = kb * 16 + (e & 15);
        const float w0 = Wr[(size_t)e * WROW + k];
        const float w1 = Wr[(size_t)e * WROW + k + 1];
        const u16 h0 = bf16rne(w0);
        const u16 h1 = bf16rne(w1);
        const u16 l0 = bf16rne(w0 - __uint_as_float((u32)h0 << 16));
        const u16 l1 = bf16rne(w1 - __uint_as_float((u32)h1 << 16));
        const u32 oi = (u32)(((step * 4 + grp) * 64 + lane) * 4 + d);
        wh[oi] = ((u32)h1 << 16) | h0;
        wl[oi] = ((u32)l1 << 16) | l0;
    } else {
        __shared__ float tp[4][16];
        if (t < 64) {
            const int b = t >> 4, r = t & 15;
            float s = bp[r];
            #pragma unroll
            for (int i = 0; i < 16; ++i) s += z[b * 16 + i] * Wp[r * 16 + i];
            tp[b][r] = 0.5f * s * (1.0f + erff(s * 0.70710678118654752440f));
        }
        #pragma unroll
        for (int i = t; i < 1024; i += 256) wsb[256 + i] = 0.0f;
        __syncthreads();
        {
            const int b = t >> 6, e = t & 63;
            const float* wr = Wr + (size_t)e * WROW + DDIM;
            float s = eb[e];
            #pragma unroll
            for (int i = 0; i < 16; ++i) s += tp[b][i] * wr[i];
            wsb[b * 64 + e] = s;
        }
    }
}

// ---------------- kernel 2: MFMA logits + softmax + top2 + probs + P/f -----------
// 576 thr: waves 0..7 consumers (tg = wv&3, h = wv>>2), wave 8 producer.
// LDS: smem[0..16384) u32 = B ring 4x16KB ; lg f32[2][64*68] (34.8KB) ALIASES ring
// (post-loop only; all DMAs drained at t=30); pf = smem[16384..17408) (4KB).
__global__ __launch_bounds__(576, 1) void k2_mfma(const float* __restrict__ x,
                                                  const float* __restrict__ wsb,
                                                  const u32* __restrict__ whp,
                                                  const u32* __restrict__ wlp,
                                                  float* __restrict__ wacc,
                                                  float* __restrict__ out) {
    __shared__ __align__(16) u32 smem[17408];      // 68 KB total
    float* const lgf = (float*)smem;               // [2][64*68], post-loop only
    float* const pff = (float*)&smem[16384];       // [8*128]

    const int tid   = threadIdx.x;
    const int wv    = __builtin_amdgcn_readfirstlane(tid >> 6);
    const int lane  = tid & 63;
    const int tok0b = blockIdx.x * 64;
    const int bb    = tok0b >> 12;    // batch (uniform per block)

    if (wv == 8) {
        // ---- producer: B-frag DMA, 4-deep ring; vmcnt = DMAs only ----------------
#define BDMA(t, buf) do {                                                       \
            _Pragma("unroll")                                                   \
            for (int hl = 0; hl < 2; ++hl)                                      \
            _Pragma("unroll")                                                   \
            for (int hh = 0; hh < 2; ++hh)                                      \
            _Pragma("unroll")                                                   \
            for (int g = 0; g < 4; ++g) {                                       \
                const u32* _s = (hl ? wlp : whp) +                              \
                                ((t) + hh * 32) * 1024 + g * 256 + lane * 4;    \
                u32* _d = &smem[(buf) * 4096 + hl * 2048 + hh * 1024 + g * 256 + lane * 4];\
                __builtin_amdgcn_global_load_lds((gp1)_s, (lp3)_d, 16, 0, 0);   \
            }                                                                   \
        } while (0)
#define PSTEP(t, j) do {                                                        \
            BDMA((t) + 3, ((j) + 3) & 3);                                       \
            asm volatile("s_waitcnt vmcnt(32)" ::: "memory");                   \
            BAR();                                                              \
        } while (0)
        BDMA(0, 0); BDMA(1, 1); BDMA(2, 2);
        asm volatile("s_waitcnt vmcnt(32)" ::: "memory");   // batch 0 landed
        BAR();                                              // consumers start t=0
        for (int g7 = 0; g7 < 7; ++g7) {                    // t = 0..27
            const int t0 = g7 * 4;
            PSTEP(t0 + 0, 0); PSTEP(t0 + 1, 1);
            PSTEP(t0 + 2, 2); PSTEP(t0 + 3, 3);
        }
        // epilogue t=28..31
        BDMA(31, 3);
        asm volatile("s_waitcnt vmcnt(32)" ::: "memory"); BAR();   // t=28 (29 landed)
        asm volatile("s_waitcnt vmcnt(16)" ::: "memory"); BAR();   // t=29 (30 landed)
        asm volatile("s_waitcnt vmcnt(0)"  ::: "memory"); BAR();   // t=30 (31 landed)
        BAR();                                                     // t=31
#undef BDMA
#undef PSTEP
    } else {
        // ---------------- consumer: vmcnt = x ring only ---------------------------
        const int tg  = wv & 3;
        const int h   = wv >> 2;
        const int row = lane & 15;    // token within 16-tile (A row)
        const int kg  = lane >> 4;    // k-group 0..3
        const int tok0 = tok0b + tg * 16;

        f32x4 acc[4];
        #pragma unroll
        for (int g = 0; g < 4; ++g) {
            const float tl = (h == 0) ? wsb[bb * 64 + g * 16 + row] : 0.0f;
            acc[g] = (f32x4){tl, tl, tl, tl};
        }
        #pragma unroll
        for (int g = 0; g < 4; ++g) asm volatile("" : "+v"(acc[g]));
        __builtin_amdgcn_sched_barrier(0);       // wsb-load wait lands before ring

        u64 xcur = (u64)(x + (size_t)(tok0 + row) * DDIM + h * 1024 + kg * 8);
        f32x4 xr[4][2];                          // depth-4 ring (32 VGPR)

        // bf16 hi/lo split via v_cvt_pk_bf16_f32 (RNE, == manual bf16rne)
#define SPLIT(xa, xb, Ah, Al) do {                                              \
            u32 h0_, h1_, h2_, h3_, l0_, l1_, l2_, l3_;                         \
            asm("v_cvt_pk_bf16_f32 %0, %1, %2" : "=v"(h0_) : "v"((xa)[0]), "v"((xa)[1])); \
            asm("v_cvt_pk_bf16_f32 %0, %1, %2" : "=v"(h1_) : "v"((xa)[2]), "v"((xa)[3])); \
            asm("v_cvt_pk_bf16_f32 %0, %1, %2" : "=v"(h2_) : "v"((xb)[0]), "v"((xb)[1])); \
            asm("v_cvt_pk_bf16_f32 %0, %1, %2" : "=v"(h3_) : "v"((xb)[2]), "v"((xb)[3])); \
            const float r0_ = (xa)[0] - __uint_as_float(h0_ << 16);             \
            const float r1_ = (xa)[1] - __uint_as_float(h0_ & 0xFFFF0000u);     \
            const float r2_ = (xa)[2] - __uint_as_float(h1_ << 16);             \
            const float r3_ = (xa)[3] - __uint_as_float(h1_ & 0xFFFF0000u);     \
            const float r4_ = (xb)[0] - __uint_as_float(h2_ << 16);             \
            const float r5_ = (xb)[1] - __uint_as_float(h2_ & 0xFFFF0000u);     \
            const float r6_ = (xb)[2] - __uint_as_float(h3_ << 16);             \
            const float r7_ = (xb)[3] - __uint_as_float(h3_ & 0xFFFF0000u);     \
            asm("v_cvt_pk_bf16_f32 %0, %1, %2" : "=v"(l0_) : "v"(r0_), "v"(r1_)); \
            asm("v_cvt_pk_bf16_f32 %0, %1, %2" : "=v"(l1_) : "v"(r2_), "v"(r3_)); \
            asm("v_cvt_pk_bf16_f32 %0, %1, %2" : "=v"(l2_) : "v"(r4_), "v"(r5_)); \
            asm("v_cvt_pk_bf16_f32 %0, %1, %2" : "=v"(l3_) : "v"(r6_), "v"(r7_)); \
            const u32x4 uh_ = {h0_, h1_, h2_, h3_};                             \
            const u32x4 ul_ = {l0_, l1_, l2_, l3_};                             \
            Ah = __builtin_bit_cast(short8, uh_);                               \
            Al = __builtin_bit_cast(short8, ul_);                               \
        } while (0)

#define MSTEP(xa, xb, BH, BL) do {                                              \
            short8 Ah, Al;                                                      \
            SPLIT(xa, xb, Ah, Al);                                              \
            _Pragma("unroll")                                                   \
            for (int g = 0; g < 4; ++g) {                                       \
                acc[g] = __builtin_amdgcn_mfma_f32_16x16x32_bf16(Ah, BH[g], acc[g], 0, 0, 0); \
                acc[g] = __builtin_amdgcn_mfma_f32_16x16x32_bf16(Ah, BL[g], acc[g], 0, 0, 0); \
                acc[g] = __builtin_amdgcn_mfma_f32_16x16x32_bf16(Al, BH[g], acc[g], 0, 0, 0); \
                acc[g] = __builtin_amdgcn_mfma_f32_16x16x32_bf16(Al, BL[g], acc[g], 0, 0, 0); \
            }                                                                   \
        } while (0)

        // consumer step j (=t&3): B from buf j, wait ring slot j, MFMA, refill slot j
#define CSTEP(j, WAITN, DOLOAD) do {                                            \
            short8 BH[4], BL[4];                                                \
            _Pragma("unroll")                                                   \
            for (int g2 = 0; g2 < 4; ++g2) {                                    \
                BH[g2] = *(const short8*)&smem[(j) * 4096 + h * 1024 + g2 * 256 + lane * 4]; \
                BL[g2] = *(const short8*)&smem[(j) * 4096 + 2048 + h * 1024 + g2 * 256 + lane * 4]; \
            }                                                                   \
            asm volatile("s_waitcnt vmcnt(" #WAITN ")"                          \
                : "+v"(xr[j][0]), "+v"(xr[j][1]));                              \
            __builtin_amdgcn_sched_barrier(0);                                  \
            MSTEP(xr[j][0], xr[j][1], BH, BL);                                  \
            if (DOLOAD) {                                                       \
                asm volatile("global_load_dwordx4 %0, %1, off offset:%c2"       \
                    : "=&v"(xr[j][0]) : "v"(xcur), "i"(((j) + 4) * 128));       \
                asm volatile("global_load_dwordx4 %0, %1, off offset:%c2"       \
                    : "=&v"(xr[j][1]) : "v"(xcur), "i"(((j) + 4) * 128 + 16));  \
            }                                                                   \
            BAR();                                                              \
        } while (0)

        // prologue: fill ring slots 0..3 (steps 0..3)
        #pragma unroll
        for (int j = 0; j < 4; ++j) {
            asm volatile("global_load_dwordx4 %0, %1, off offset:%c2"
                : "=&v"(xr[j][0]) : "v"(xcur), "i"(j * 128));
            asm volatile("global_load_dwordx4 %0, %1, off offset:%c2"
                : "=&v"(xr[j][1]) : "v"(xcur), "i"(j * 128 + 16));
        }
        BAR();                                   // B(0) ready
        for (int g7 = 0; g7 < 7; ++g7) {         // t = 0..27
            CSTEP(0, 6, 1); CSTEP(1, 6, 1); CSTEP(2, 6, 1); CSTEP(3, 6, 1);
            xcur += 512;                         // next 4-step group
        }
        // epilogue t=28..31: no refills; waits drain the ring to zero
        CSTEP(0, 6, 0); CSTEP(1, 4, 0); CSTEP(2, 2, 0); CSTEP(3, 0, 0);
#undef SPLIT
#undef MSTEP
#undef CSTEP

        // ---- partial-logit exchange into ALIASED lg (post-loop only) -------------
        #pragma unroll
        for (int g = 0; g < 4; ++g)
            #pragma unroll
            for (int r = 0; r < 4; ++r)
                lgf[h * 4352 + (tg * 16 + kg * 4 + r) * 68 + g * 16 + row] = acc[g][r];
    }

    __syncthreads();

    // ---- softmax/top2 for tokens wv*8 .. wv*8+7 ; lane = expert (consumers) ----
    if (wv < 8) {
        float pacc = 0.0f, facc = 0.0f;
        for (int i = 0; i < 8; ++i) {
            const int tk = wv * 8 + i;
            const float v = lgf[tk * 68 + lane] + lgf[4352 + tk * 68 + lane];
            float m1 = v; int i1 = lane;
            #pragma unroll
            for (int off = 32; off; off >>= 1) {
                const float ov = __shfl_xor(m1, off, 64);
                const int   oi = __shfl_xor(i1, off, 64);
                if (ov > m1 || (ov == m1 && oi < i1)) { m1 = ov; i1 = oi; }
            }
            const float vx = (lane == i1) ? -3.4e38f : v;
            float m2 = vx; int i2 = lane;
            #pragma unroll
            for (int off = 32; off; off >>= 1) {
                const float ov = __shfl_xor(m2, off, 64);
                const int   oi = __shfl_xor(i2, off, 64);
                if (ov > m2 || (ov == m2 && oi < i2)) { m2 = ov; i2 = oi; }
            }
            const float p = __expf(v - m1);
            float s = p;
            #pragma unroll
            for (int off = 32; off; off >>= 1) s += __shfl_xor(s, off, 64);
            const float rZ = 1.0f / s;
            const float pn = p * rZ;
            const int   T  = tok0b + tk;
            out[65536 + (size_t)T * 64 + lane] = pn;      // coalesced 256 B
            pacc += pn;
            facc += (lane == i1 ? 1.0f : 0.0f) + (lane == i2 ? 1.0f : 0.0f);
            if (lane == 0) {
                const float q1 = rZ, q2 = __expf(m2 - m1) * rZ;
                const float dn = 1.0f / (q1 + q2 + 1e-8f);
                float2 tw; tw.x = q1 * dn; tw.y = q2 * dn;
                *(float2*)(out + (size_t)T * 2) = tw;
                float2 ti; ti.x = (float)i1; ti.y = (float)i2;
                *(float2*)(out + 32768 + (size_t)T * 2) = ti;
            }
        }
        pff[wv * 128 + lane]      = pacc;
        pff[wv * 128 + 64 + lane] = facc;
    }
    __syncthreads();

    // ---- block-level P/f reduce -> one atomic per address per block (8 slots) ----
    if (wv == 0) {
        float ps = 0.0f, fs = 0.0f;
        #pragma unroll
        for (int w2 = 0; w2 < 8; ++w2) {
            ps += pff[w2 * 128 + lane];
            fs += pff[w2 * 128 + 64 + lane];
        }
        const int slot = blockIdx.x & 7;
        atomicAdd(wacc + slot * 128 + lane, ps);
        atomicAdd(wacc + slot * 128 + 64 + lane, fs);
    }
}

// ---------------- kernel 3: aux loss ------------------------------------------------
__global__ void k3_aux(const float* __restrict__ wsb, float* __restrict__ out) {
    const int e = threadIdx.x;  // 64 threads
    float P = 0.0f, F = 0.0f;
    #pragma unroll
    for (int s = 0; s < 8; ++s) {
        P += wsb[256 + s * 128 + e];
        F += wsb[256 + s * 128 + 64 + e];
    }
    float val = P * F;
    #pragma unroll
    for (int off = 32; off; off >>= 1) val += __shfl_xor(val, off, 64);
    if (e == 0)
        out[1114112] = 64.0f * val / (16384.0f * 2.0f * 16384.0f);
}

extern "C" void kernel_launch(void* const* d_in, const int* in_sizes, int n_in,
                              void* d_out, int out_size, void* d_ws, size_t ws_size,
                              hipStream_t stream) {
    (void)in_sizes; (void)n_in; (void)out_size; (void)ws_size;
    const float* x  = (const float*)d_in[0];
    const float* z  = (const float*)d_in[1];
    const float* Wr = (const float*)d_in[2];
    const float* Wp = (const float*)d_in[3];
    const float* bp = (const float*)d_in[4];
    const float* eb = (const float*)d_in[5];
    float* out = (float*)d_out;
    float* wsb = (float*)d_ws;
    u32*   wfH = (u32*)(wsb + 1280);          // 65536 u32 (256 KB)
    u32*   wfL = wfH + 65536;                 // 65536 u32 (256 KB)

    hipLaunchKernelGGL(k01_prep, dim3(257), dim3(256), 0, stream,
                       Wr, wfH, wfL, z, Wp, bp, eb, wsb);
    hipLaunchKernelGGL(k2_mfma,  dim3(256), dim3(576), 0, stream, x, wsb,
                       wfH, wfL, wsb + 256, out);
    hipLaunchKernelGGL(k3_aux,   dim3(1),   dim3(64),  0, stream, wsb, out);
}